// Round 1
// baseline (774.726 us; speedup 1.0000x reference)
//
#include <hip/hip_runtime.h>
#include <hip/hip_bf16.h>

// C[8192,1000] = sign(X) @ sign(W)^T via i8 MFMA (values in {-1,0,+1}).
// pack_w: W fp32 -> i8, pre-tiled [stage][n(1024)][64B] in d_ws.
// bgemm: 256 WGs = 128 M-tiles(64 rows) x split-K 2. Per WG: 8 waves.
//   Wave tile 32x256 (2 M-halves x 4 N-slabs): halves per-CU A LDS-read
//   broadcast traffic vs 64x128 (LDS pipe was binding: 32 ds_read_b128/stage
//   ~384cyc vs 326cyc MFMA). K-chunk = 128 (2 stages) per barrier,
//   register-prefetched X staging into XOR-swizzled double-buffered LDS
//   (swizzle verified conflict-free), B frags direct global->VGPR from L2/L1.
// Split-K partials: i16 halves of one dword in ws (disjoint bytes, no race),
//   reduce kernel sums -> float out. Fallback: zero + atomicAdd if ws small.

#define K_DIM   12288
#define N_CLS   1000
#define N_PAD   1024
#define KSPLIT  2
#define K_HALF  (K_DIM / KSPLIT)         // 6144
#define STAGE_BYTES (N_PAD * 64)         // 65536
#define N_STAGE_TOT (K_DIM / 64)         // 192
#define CHUNK_STAGES 2
#define CHUNK_K  (CHUNK_STAGES * 64)     // 128
#define CHUNKS   (K_HALF / CHUNK_K)      // 48
#define M_TILE   64
#define B_ROWS   8192
#define WS_W_BYTES ((size_t)N_STAGE_TOT * STAGE_BYTES)     // 12,582,912
#define WS_P_BYTES ((size_t)B_ROWS * N_CLS * 4)            // 32,768,000

typedef int int4v __attribute__((ext_vector_type(4)));
typedef unsigned int uint4v __attribute__((ext_vector_type(4)));

// sign byte: +1 / -1 / 0 (handles +-0.0 exactly)
__device__ __forceinline__ unsigned sign_byte(unsigned bits) {
    unsigned mag = bits & 0x7fffffffu;
    unsigned nz = mag ? 1u : 0u;
    int sgn = ((int)bits) >> 31;
    int v = (((int)nz) ^ sgn) - sgn;
    return (unsigned)(v & 0xff);
}

__device__ __forceinline__ unsigned pack4(uint4v b) {
    return sign_byte(b.x) | (sign_byte(b.y) << 8) |
           (sign_byte(b.z) << 16) | (sign_byte(b.w) << 24);
}

// ---- W pre-pass: one thread -> 16 consecutive packed bytes of (stage, n).
// Wave writes 1 KB contiguous (16 n-rows x 64 B of one stage).
__global__ void pack_w_kernel(const float* __restrict__ w,
                              unsigned char* __restrict__ ws) {
    const int gid = blockIdx.x * 256 + threadIdx.x;   // 786432 total
    const int stage = gid >> 12;                      // 0..191
    const int n = (gid >> 2) & 1023;
    const int q16 = gid & 3;
    const int k = stage * 64 + q16 * 16;
    uint4v o = {0u, 0u, 0u, 0u};
    if (n < N_CLS) {
        const float* p = w + (size_t)n * K_DIM + k;
        o.x = pack4(*reinterpret_cast<const uint4v*>(p));
        o.y = pack4(*reinterpret_cast<const uint4v*>(p + 4));
        o.z = pack4(*reinterpret_cast<const uint4v*>(p + 8));
        o.w = pack4(*reinterpret_cast<const uint4v*>(p + 12));
    }
    *reinterpret_cast<uint4v*>(ws + (size_t)stage * STAGE_BYTES + n * 64 + q16 * 16) = o;
}

__global__ void zero_kernel(float* __restrict__ out) {
    const int i = blockIdx.x * 256 + threadIdx.x;     // 2,048,000 float4
    float4 z = {0.f, 0.f, 0.f, 0.f};
    *reinterpret_cast<float4*>(out + (size_t)i * 4) = z;
}

__global__ void reduce_kernel(const unsigned* __restrict__ part,
                              float* __restrict__ out) {
    const int i = blockIdx.x * 256 + threadIdx.x;     // 2,048,000 uint4
    uint4v w = *reinterpret_cast<const uint4v*>(part + (size_t)i * 4);
    float4 f;
    f.x = (float)((int)(short)(w.x & 0xffffu) + (int)(short)(w.x >> 16));
    f.y = (float)((int)(short)(w.y & 0xffffu) + (int)(short)(w.y >> 16));
    f.z = (float)((int)(short)(w.z & 0xffffu) + (int)(short)(w.z >> 16));
    f.w = (float)((int)(short)(w.w & 0xffffu) + (int)(short)(w.w >> 16));
    *reinterpret_cast<float4*>(out + (size_t)i * 4) = f;
}

// ---- main GEMM
template<int USE_PARTIAL>
__global__ __launch_bounds__(512, 2)
void bgemm_kernel(const float* __restrict__ x,
                  const unsigned char* __restrict__ wq,
                  unsigned* __restrict__ part,
                  float* __restrict__ out) {
    // 2 buffers x 64 rows x 32 dwords (128 i8 per row), XOR-swizzled
    __shared__ unsigned x_lds[2][M_TILE * 32];

    const int tid  = threadIdx.x;
    const int wave = tid >> 6;
    const int lane = tid & 63;
    const int q    = lane >> 4;
    const int l15  = lane & 15;
    const int bx   = blockIdx.x;
    const int mtile = bx >> 1;
    const int kh    = bx & 1;
    const int m0    = mtile * M_TILE;
    const int mhalf = wave >> 2;            // 0..1: which 32-row half of the tile
    const int nbase = (wave & 3) * 256;     // 4 N-slabs of 256

    int4v acc[2][16];
#pragma unroll
    for (int i = 0; i < 2; ++i)
#pragma unroll
        for (int j = 0; j < 16; ++j)
            acc[i][j] = (int4v){0, 0, 0, 0};

    // staging: thread t -> row t>>3; i-th uint4 covers logical dword i*8+(t&7)
    const int srow = tid >> 3;
    const int scol = tid & 7;
    const float* xp = x + (size_t)(m0 + srow) * K_DIM + kh * K_HALF + scol * 4;
    const int sw_w = (srow & 3) * 8;

    const unsigned char* wqb = wq + (size_t)(kh * (N_STAGE_TOT / KSPLIT)) * STAGE_BYTES
                               + (nbase + l15) * 64 + q * 16;
    const int rsw = (l15 & 3) * 8;
    const int arow0 = (mhalf * 32 + l15) * 32;   // LDS dword row base, mt=0

    uint4v xr[4];
#pragma unroll
    for (int i = 0; i < 4; ++i)
        xr[i] = __builtin_nontemporal_load(reinterpret_cast<const uint4v*>(xp + i * 32));
#pragma unroll
    for (int i = 0; i < 4; ++i)
        x_lds[0][srow * 32 + (((i * 8 + scol)) ^ sw_w)] = pack4(xr[i]);
    __syncthreads();

#pragma unroll 2
    for (int c = 0; c < CHUNKS; ++c) {
        const int cur = c & 1;
        if (c + 1 < CHUNKS) {
            const float* xpc = xp + (size_t)(c + 1) * CHUNK_K;
#pragma unroll
            for (int i = 0; i < 4; ++i)
                xr[i] = __builtin_nontemporal_load(reinterpret_cast<const uint4v*>(xpc + i * 32));
        }
        const unsigned char* wpc = wqb + (size_t)(c * CHUNK_STAGES) * STAGE_BYTES;
#pragma unroll
        for (int st = 0; st < CHUNK_STAGES; ++st) {
            int4v a[2];
#pragma unroll
            for (int mt = 0; mt < 2; ++mt)
                a[mt] = *reinterpret_cast<const int4v*>(
                    &x_lds[cur][arow0 + mt * (16 * 32) + ((st * 16 + q * 4) ^ rsw)]);
            const unsigned char* wp = wpc + st * STAGE_BYTES;
#pragma unroll
            for (int nt = 0; nt < 16; ++nt) {
                int4v b = *reinterpret_cast<const int4v*>(wp + nt * 1024);
                acc[0][nt] = __builtin_amdgcn_mfma_i32_16x16x64_i8(a[0], b, acc[0][nt], 0, 0, 0);
                acc[1][nt] = __builtin_amdgcn_mfma_i32_16x16x64_i8(a[1], b, acc[1][nt], 0, 0, 0);
            }
        }
        if (c + 1 < CHUNKS) {
#pragma unroll
            for (int i = 0; i < 4; ++i)
                x_lds[cur ^ 1][srow * 32 + (((i * 8 + scol)) ^ sw_w)] = pack4(xr[i]);
        }
        __syncthreads();
    }

    // epilogue: D col(N) = l15 offset, row(M) = q*4 + reg
#pragma unroll
    for (int mt = 0; mt < 2; ++mt) {
#pragma unroll
        for (int nt = 0; nt < 16; ++nt) {
            const int col = nbase + nt * 16 + l15;
            if (col < N_CLS) {
#pragma unroll
                for (int r = 0; r < 4; ++r) {
                    const int row = m0 + mhalf * 32 + mt * 16 + q * 4 + r;
                    const size_t idx = (size_t)row * N_CLS + col;
                    if (USE_PARTIAL) {
                        reinterpret_cast<short*>(part)[idx * 2 + kh] = (short)acc[mt][nt][r];
                    } else {
                        atomicAdd(&out[idx], (float)acc[mt][nt][r]);
                    }
                }
            }
        }
    }
}

extern "C" void kernel_launch(void* const* d_in, const int* in_sizes, int n_in,
                              void* d_out, int out_size, void* d_ws, size_t ws_size,
                              hipStream_t stream) {
    const float* x = (const float*)d_in[0];     // [8192, 12288]
    const float* w = (const float*)d_in[1];     // [1000, 12288]
    float* out = (float*)d_out;                 // [8192, 1000]
    unsigned char* ws = (unsigned char*)d_ws;

    pack_w_kernel<<<3072, 256, 0, stream>>>(w, ws);

    unsigned* part = reinterpret_cast<unsigned*>(ws + WS_W_BYTES);
    const bool use_part = ws_size >= WS_W_BYTES + WS_P_BYTES;
    if (use_part) {
        bgemm_kernel<1><<<256, 512, 0, stream>>>(x, ws, part, out);
        reduce_kernel<<<(B_ROWS * N_CLS) / (4 * 256), 256, 0, stream>>>(part, out);
    } else {
        zero_kernel<<<(B_ROWS * N_CLS) / (4 * 256), 256, 0, stream>>>(out);
        bgemm_kernel<0><<<256, 512, 0, stream>>>(x, ws, part, out);
    }
}

// Round 2
// 720.326 us; speedup vs baseline: 1.0755x; 1.0755x over previous
//
#include <hip/hip_runtime.h>
#include <hip/hip_bf16.h>

// C[8192,1000] = sign(X) @ sign(W)^T via i8 MFMA (values in {-1,0,+1}).
// pack_w: W fp32 -> i8, pre-tiled [stage][n(1024)][64B] in d_ws.
// bgemm: 256 WGs = 64 M-tiles(128 rows) x 2 N-split(512) x split-K 2.
//   8 waves, wave tile 128Mx64N: a[8] LDS frags, 4 B-loads, 32 MFMA/stage
//   -> B:MFMA = 1:8 (B-delivery through L2/L3 is the binding pipe; round-1's
//   32x256 tile doubled B volume and regressed 2.4x). No B duplication in WG.
//   blockIdx = ns*128 + mtile*2 + kh: ns-partners (sharing X rows) land on the
//   SAME XCD (delta 128 % 8 == 0) so the partner X read hits L2; each XCD
//   touches a single kh half of B. X loads are plain (not nontemporal) so the
//   partner can hit them in L2.
//   K-chunk = 128 (2 stages) per barrier, register-prefetched X staging
//   (128B contiguous per thread, 2x ds_write_b128) into XOR-swizzled
//   ((row&7)*4) double-buffered LDS; verified conflict-free on write+read.
// Split-K partials: i16 halves of one dword in ws (disjoint bytes, no race),
//   reduce kernel sums -> float out. Fallback: zero + atomicAdd if ws small.

#define K_DIM   12288
#define N_CLS   1000
#define N_PAD   1024
#define KSPLIT  2
#define K_HALF  (K_DIM / KSPLIT)         // 6144
#define STAGE_BYTES (N_PAD * 64)         // 65536
#define N_STAGE_TOT (K_DIM / 64)         // 192
#define CHUNK_STAGES 2
#define CHUNK_K  (CHUNK_STAGES * 64)     // 128
#define CHUNKS   (K_HALF / CHUNK_K)      // 48
#define M_TILE   128
#define B_ROWS   8192
#define WS_W_BYTES ((size_t)N_STAGE_TOT * STAGE_BYTES)     // 12,582,912
#define WS_P_BYTES ((size_t)B_ROWS * N_CLS * 4)            // 32,768,000

typedef int int4v __attribute__((ext_vector_type(4)));
typedef unsigned int uint4v __attribute__((ext_vector_type(4)));

// sign byte: +1 / -1 / 0 (handles +-0.0 exactly)
__device__ __forceinline__ unsigned sign_byte(unsigned bits) {
    unsigned mag = bits & 0x7fffffffu;
    unsigned nz = mag ? 1u : 0u;
    int sgn = ((int)bits) >> 31;
    int v = (((int)nz) ^ sgn) - sgn;
    return (unsigned)(v & 0xff);
}

__device__ __forceinline__ unsigned pack4(uint4v b) {
    return sign_byte(b.x) | (sign_byte(b.y) << 8) |
           (sign_byte(b.z) << 16) | (sign_byte(b.w) << 24);
}

// ---- W pre-pass: one thread -> 16 consecutive packed bytes of (stage, n).
// Wave writes 1 KB contiguous (16 n-rows x 64 B of one stage).
__global__ void pack_w_kernel(const float* __restrict__ w,
                              unsigned char* __restrict__ ws) {
    const int gid = blockIdx.x * 256 + threadIdx.x;   // 786432 total
    const int stage = gid >> 12;                      // 0..191
    const int n = (gid >> 2) & 1023;
    const int q16 = gid & 3;
    const int k = stage * 64 + q16 * 16;
    uint4v o = {0u, 0u, 0u, 0u};
    if (n < N_CLS) {
        const float* p = w + (size_t)n * K_DIM + k;
        o.x = pack4(*reinterpret_cast<const uint4v*>(p));
        o.y = pack4(*reinterpret_cast<const uint4v*>(p + 4));
        o.z = pack4(*reinterpret_cast<const uint4v*>(p + 8));
        o.w = pack4(*reinterpret_cast<const uint4v*>(p + 12));
    }
    *reinterpret_cast<uint4v*>(ws + (size_t)stage * STAGE_BYTES + n * 64 + q16 * 16) = o;
}

__global__ void zero_kernel(float* __restrict__ out) {
    const int i = blockIdx.x * 256 + threadIdx.x;     // 2,048,000 float4
    float4 z = {0.f, 0.f, 0.f, 0.f};
    *reinterpret_cast<float4*>(out + (size_t)i * 4) = z;
}

__global__ void reduce_kernel(const unsigned* __restrict__ part,
                              float* __restrict__ out) {
    const int i = blockIdx.x * 256 + threadIdx.x;     // 2,048,000 uint4
    uint4v w = *reinterpret_cast<const uint4v*>(part + (size_t)i * 4);
    float4 f;
    f.x = (float)((int)(short)(w.x & 0xffffu) + (int)(short)(w.x >> 16));
    f.y = (float)((int)(short)(w.y & 0xffffu) + (int)(short)(w.y >> 16));
    f.z = (float)((int)(short)(w.z & 0xffffu) + (int)(short)(w.z >> 16));
    f.w = (float)((int)(short)(w.w & 0xffffu) + (int)(short)(w.w >> 16));
    *reinterpret_cast<float4*>(out + (size_t)i * 4) = f;
}

// ---- main GEMM
template<int USE_PARTIAL>
__global__ __launch_bounds__(512, 2)
void bgemm_kernel(const float* __restrict__ x,
                  const unsigned char* __restrict__ wq,
                  unsigned* __restrict__ part,
                  float* __restrict__ out) {
    // 2 buffers x 128 rows x 32 dwords (128 i8 per row), XOR-swizzled (row&7)*4
    __shared__ unsigned x_lds[2][M_TILE * 32];

    const int tid  = threadIdx.x;
    const int wave = tid >> 6;
    const int lane = tid & 63;
    const int q    = lane >> 4;
    const int l15  = lane & 15;
    const int bx   = blockIdx.x;
    const int ns    = bx >> 7;              // 0..1 : N half
    const int rem   = bx & 127;
    const int mtile = rem >> 1;             // 0..63
    const int kh    = rem & 1;              // 0..1 : K half
    const int m0    = mtile * M_TILE;
    const int nbase = ns * 512 + wave * 64; // wave owns 64 n-rows

    int4v acc[8][4];
#pragma unroll
    for (int i = 0; i < 8; ++i)
#pragma unroll
        for (int j = 0; j < 4; ++j)
            acc[i][j] = (int4v){0, 0, 0, 0};

    // staging: thread t -> row t>>2, covers dwords [scol*8, scol*8+8) of the
    // 32-dword chunk row; global read is 128B contiguous per thread.
    const int srow = tid >> 2;
    const int scol = tid & 3;
    const float* xp = x + (size_t)(m0 + srow) * K_DIM + kh * K_HALF + scol * 32;
    const int swsh = (srow & 7) * 4;
    const int wb0  = srow * 32 + ((scol * 8 + 0) ^ swsh);
    const int wb1  = srow * 32 + ((scol * 8 + 4) ^ swsh);

    const unsigned char* wqb = wq + (size_t)(kh * (N_STAGE_TOT / KSPLIT)) * STAGE_BYTES
                               + (nbase + l15) * 64 + q * 16;
    const int rsw = (l15 & 7) * 4;

    uint4v xr[8];
#pragma unroll
    for (int i = 0; i < 8; ++i)
        xr[i] = *reinterpret_cast<const uint4v*>(xp + i * 4);
    {
        unsigned pk[8];
#pragma unroll
        for (int i = 0; i < 8; ++i) pk[i] = pack4(xr[i]);
        int4v v0 = {(int)pk[0], (int)pk[1], (int)pk[2], (int)pk[3]};
        int4v v1 = {(int)pk[4], (int)pk[5], (int)pk[6], (int)pk[7]};
        *reinterpret_cast<int4v*>(&x_lds[0][wb0]) = v0;
        *reinterpret_cast<int4v*>(&x_lds[0][wb1]) = v1;
    }
    __syncthreads();

#pragma unroll 2
    for (int c = 0; c < CHUNKS; ++c) {
        const int cur = c & 1;
        if (c + 1 < CHUNKS) {
            const float* xpc = xp + (size_t)(c + 1) * CHUNK_K;
#pragma unroll
            for (int i = 0; i < 8; ++i)
                xr[i] = *reinterpret_cast<const uint4v*>(xpc + i * 4);
        }
        const unsigned char* wpc = wqb + (size_t)(c * CHUNK_STAGES) * STAGE_BYTES;
#pragma unroll
        for (int st = 0; st < CHUNK_STAGES; ++st) {
            int4v a[8];
#pragma unroll
            for (int mt = 0; mt < 8; ++mt)
                a[mt] = *reinterpret_cast<const int4v*>(
                    &x_lds[cur][(mt * 16 + l15) * 32 + ((st * 16 + q * 4) ^ rsw)]);
            const unsigned char* wp = wpc + st * STAGE_BYTES;
#pragma unroll
            for (int nt = 0; nt < 4; ++nt) {
                int4v b = *reinterpret_cast<const int4v*>(wp + nt * 1024);
#pragma unroll
                for (int mt = 0; mt < 8; ++mt)
                    acc[mt][nt] = __builtin_amdgcn_mfma_i32_16x16x64_i8(a[mt], b, acc[mt][nt], 0, 0, 0);
            }
        }
        if (c + 1 < CHUNKS) {
            unsigned pk[8];
#pragma unroll
            for (int i = 0; i < 8; ++i) pk[i] = pack4(xr[i]);
            int4v v0 = {(int)pk[0], (int)pk[1], (int)pk[2], (int)pk[3]};
            int4v v1 = {(int)pk[4], (int)pk[5], (int)pk[6], (int)pk[7]};
            *reinterpret_cast<int4v*>(&x_lds[cur ^ 1][wb0]) = v0;
            *reinterpret_cast<int4v*>(&x_lds[cur ^ 1][wb1]) = v1;
        }
        __syncthreads();
    }

    // epilogue: D col(N) = l15 offset, row(M) = q*4 + reg
#pragma unroll
    for (int mt = 0; mt < 8; ++mt) {
#pragma unroll
        for (int nt = 0; nt < 4; ++nt) {
            const int col = nbase + nt * 16 + l15;
            if (col < N_CLS) {
#pragma unroll
                for (int r = 0; r < 4; ++r) {
                    const int row = m0 + mt * 16 + q * 4 + r;
                    const size_t idx = (size_t)row * N_CLS + col;
                    if (USE_PARTIAL) {
                        reinterpret_cast<short*>(part)[idx * 2 + kh] = (short)acc[mt][nt][r];
                    } else {
                        atomicAdd(&out[idx], (float)acc[mt][nt][r]);
                    }
                }
            }
        }
    }
}

extern "C" void kernel_launch(void* const* d_in, const int* in_sizes, int n_in,
                              void* d_out, int out_size, void* d_ws, size_t ws_size,
                              hipStream_t stream) {
    const float* x = (const float*)d_in[0];     // [8192, 12288]
    const float* w = (const float*)d_in[1];     // [1000, 12288]
    float* out = (float*)d_out;                 // [8192, 1000]
    unsigned char* ws = (unsigned char*)d_ws;

    pack_w_kernel<<<3072, 256, 0, stream>>>(w, ws);

    unsigned* part = reinterpret_cast<unsigned*>(ws + WS_W_BYTES);
    const bool use_part = ws_size >= WS_W_BYTES + WS_P_BYTES;
    if (use_part) {
        bgemm_kernel<1><<<256, 512, 0, stream>>>(x, ws, part, out);
        reduce_kernel<<<(B_ROWS * N_CLS) / (4 * 256), 256, 0, stream>>>(part, out);
    } else {
        zero_kernel<<<(B_ROWS * N_CLS) / (4 * 256), 256, 0, stream>>>(out);
        bgemm_kernel<0><<<256, 512, 0, stream>>>(x, ws, part, out);
    }
}

// Round 3
// 702.528 us; speedup vs baseline: 1.1028x; 1.0253x over previous
//
#include <hip/hip_runtime.h>
#include <hip/hip_bf16.h>

// C[8192,1000] = sign(X) @ sign(W)^T via i8 MFMA (values in {-1,0,+1}).
// pack_w: W fp32 -> i8, pre-tiled [stage][n(1024)][64B] in d_ws.
// bgemm: 512 WGs = 128 M-tiles(64 rows) x split-K 4  -> 2 blocks/CU
//   (round-2 counters: Occupancy 23%, all pipes idle -> latency-bound at
//   1 block/CU; barrier drain had no co-resident block to hide under).
//   8 waves x N=128 (round-0 tile, best measured), K-chunk = 128 (2 stages)
//   per barrier, register-prefetched X staging into XOR-swizzled
//   double-buffered LDS, B frags direct global->VGPR from L2.
//   bx = mtile*4 + kh -> XCD (bx%8) serves a single kh quarter: per-XCD B
//   working set 3.1 MB < 4 MiB L2. X loads nontemporal (read-once; keep L2
//   for B).
// Split-K partials: 4 x i16 per output (|partial| <= 3072), disjoint bytes,
//   no race; reduce kernel sums 4 shorts -> float. Fallback: zero+atomicAdd.

#define K_DIM   12288
#define N_CLS   1000
#define N_PAD   1024
#define KSPLIT  4
#define K_QUART (K_DIM / KSPLIT)         // 3072
#define STAGE_BYTES (N_PAD * 64)         // 65536
#define N_STAGE_TOT (K_DIM / 64)         // 192
#define CHUNK_STAGES 2
#define CHUNK_K  (CHUNK_STAGES * 64)     // 128
#define CHUNKS   (K_QUART / CHUNK_K)     // 24
#define M_TILE   64
#define B_ROWS   8192
#define WS_W_BYTES ((size_t)N_STAGE_TOT * STAGE_BYTES)     // 12,582,912
#define WS_P_BYTES ((size_t)B_ROWS * N_CLS * 2 * KSPLIT)   // 65,536,000

typedef int int4v __attribute__((ext_vector_type(4)));
typedef unsigned int uint4v __attribute__((ext_vector_type(4)));

// sign byte: +1 / -1 / 0 (handles +-0.0 exactly)
__device__ __forceinline__ unsigned sign_byte(unsigned bits) {
    unsigned mag = bits & 0x7fffffffu;
    unsigned nz = mag ? 1u : 0u;
    int sgn = ((int)bits) >> 31;
    int v = (((int)nz) ^ sgn) - sgn;
    return (unsigned)(v & 0xff);
}

__device__ __forceinline__ unsigned pack4(uint4v b) {
    return sign_byte(b.x) | (sign_byte(b.y) << 8) |
           (sign_byte(b.z) << 16) | (sign_byte(b.w) << 24);
}

// ---- W pre-pass: one thread -> 16 consecutive packed bytes of (stage, n).
__global__ void pack_w_kernel(const float* __restrict__ w,
                              unsigned char* __restrict__ ws) {
    const int gid = blockIdx.x * 256 + threadIdx.x;   // 786432 total
    const int stage = gid >> 12;                      // 0..191
    const int n = (gid >> 2) & 1023;
    const int q16 = gid & 3;
    const int k = stage * 64 + q16 * 16;
    uint4v o = {0u, 0u, 0u, 0u};
    if (n < N_CLS) {
        const float* p = w + (size_t)n * K_DIM + k;
        o.x = pack4(*reinterpret_cast<const uint4v*>(p));
        o.y = pack4(*reinterpret_cast<const uint4v*>(p + 4));
        o.z = pack4(*reinterpret_cast<const uint4v*>(p + 8));
        o.w = pack4(*reinterpret_cast<const uint4v*>(p + 12));
    }
    *reinterpret_cast<uint4v*>(ws + (size_t)stage * STAGE_BYTES + n * 64 + q16 * 16) = o;
}

__global__ void zero_kernel(float* __restrict__ out) {
    const int i = blockIdx.x * 256 + threadIdx.x;     // 2,048,000 float4
    float4 z = {0.f, 0.f, 0.f, 0.f};
    *reinterpret_cast<float4*>(out + (size_t)i * 4) = z;
}

// 4 partial shorts per output; thread handles 4 outputs (2x uint4 read, float4 write)
__global__ void reduce_kernel(const unsigned* __restrict__ part,
                              float* __restrict__ out) {
    const int i = blockIdx.x * 256 + threadIdx.x;     // 2,048,000
    uint4v w0 = *reinterpret_cast<const uint4v*>(part + (size_t)i * 8);
    uint4v w1 = *reinterpret_cast<const uint4v*>(part + (size_t)i * 8 + 4);
    float4 f;
    f.x = (float)((int)(short)(w0.x & 0xffffu) + (int)(short)(w0.x >> 16)
                + (int)(short)(w0.y & 0xffffu) + (int)(short)(w0.y >> 16));
    f.y = (float)((int)(short)(w0.z & 0xffffu) + (int)(short)(w0.z >> 16)
                + (int)(short)(w0.w & 0xffffu) + (int)(short)(w0.w >> 16));
    f.z = (float)((int)(short)(w1.x & 0xffffu) + (int)(short)(w1.x >> 16)
                + (int)(short)(w1.y & 0xffffu) + (int)(short)(w1.y >> 16));
    f.w = (float)((int)(short)(w1.z & 0xffffu) + (int)(short)(w1.z >> 16)
                + (int)(short)(w1.w & 0xffffu) + (int)(short)(w1.w >> 16));
    *reinterpret_cast<float4*>(out + (size_t)i * 4) = f;
}

// ---- main GEMM
template<int USE_PARTIAL>
__global__ __launch_bounds__(512, 2)
void bgemm_kernel(const float* __restrict__ x,
                  const unsigned char* __restrict__ wq,
                  unsigned* __restrict__ part,
                  float* __restrict__ out) {
    // 2 buffers x 64 rows x 32 dwords (128 i8 per row), XOR-swizzled
    __shared__ unsigned x_lds[2][M_TILE * 32];

    const int tid  = threadIdx.x;
    const int wave = tid >> 6;
    const int lane = tid & 63;
    const int q    = lane >> 4;
    const int l15  = lane & 15;
    const int bx   = blockIdx.x;
    const int mtile = bx >> 2;              // 0..127
    const int kh    = bx & 3;               // 0..3 : K quarter; XCD=bx%8 pins kh
    const int m0    = mtile * M_TILE;
    const int nbase = wave * 128;

    int4v acc[4][8];
#pragma unroll
    for (int i = 0; i < 4; ++i)
#pragma unroll
        for (int j = 0; j < 8; ++j)
            acc[i][j] = (int4v){0, 0, 0, 0};

    // staging: thread t -> row t>>3; i-th uint4 covers logical dword i*8+(t&7)
    const int srow = tid >> 3;
    const int scol = tid & 7;
    const float* xp = x + (size_t)(m0 + srow) * K_DIM + kh * K_QUART + scol * 4;
    const int sw_w = (srow & 3) * 8;

    const unsigned char* wqb = wq + (size_t)(kh * (N_STAGE_TOT / KSPLIT)) * STAGE_BYTES
                               + (nbase + l15) * 64 + q * 16;
    const int rsw = (l15 & 3) * 8;

    uint4v xr[4];
#pragma unroll
    for (int i = 0; i < 4; ++i)
        xr[i] = __builtin_nontemporal_load(reinterpret_cast<const uint4v*>(xp + i * 32));
#pragma unroll
    for (int i = 0; i < 4; ++i)
        x_lds[0][srow * 32 + (((i * 8 + scol)) ^ sw_w)] = pack4(xr[i]);
    __syncthreads();

#pragma unroll 2
    for (int c = 0; c < CHUNKS; ++c) {
        const int cur = c & 1;
        if (c + 1 < CHUNKS) {
            const float* xpc = xp + (size_t)(c + 1) * CHUNK_K;
#pragma unroll
            for (int i = 0; i < 4; ++i)
                xr[i] = __builtin_nontemporal_load(reinterpret_cast<const uint4v*>(xpc + i * 32));
        }
        const unsigned char* wpc = wqb + (size_t)(c * CHUNK_STAGES) * STAGE_BYTES;
#pragma unroll
        for (int st = 0; st < CHUNK_STAGES; ++st) {
            int4v a[4];
#pragma unroll
            for (int mt = 0; mt < 4; ++mt)
                a[mt] = *reinterpret_cast<const int4v*>(
                    &x_lds[cur][(mt * 16 + l15) * 32 + ((st * 16 + q * 4) ^ rsw)]);
            const unsigned char* wp = wpc + st * STAGE_BYTES;
#pragma unroll
            for (int nt = 0; nt < 8; ++nt) {
                int4v b = *reinterpret_cast<const int4v*>(wp + nt * 1024);
#pragma unroll
                for (int mt = 0; mt < 4; ++mt)
                    acc[mt][nt] = __builtin_amdgcn_mfma_i32_16x16x64_i8(a[mt], b, acc[mt][nt], 0, 0, 0);
            }
        }
        if (c + 1 < CHUNKS) {
#pragma unroll
            for (int i = 0; i < 4; ++i)
                x_lds[cur ^ 1][srow * 32 + (((i * 8 + scol)) ^ sw_w)] = pack4(xr[i]);
        }
        __syncthreads();
    }

    // epilogue: D col(N) = l15 offset, row(M) = q*4 + reg
#pragma unroll
    for (int mt = 0; mt < 4; ++mt) {
#pragma unroll
        for (int nt = 0; nt < 8; ++nt) {
            const int col = nbase + nt * 16 + l15;
            if (col < N_CLS) {
#pragma unroll
                for (int r = 0; r < 4; ++r) {
                    const int row = m0 + mt * 16 + q * 4 + r;
                    const size_t idx = (size_t)row * N_CLS + col;
                    if (USE_PARTIAL) {
                        reinterpret_cast<short*>(part)[idx * 4 + kh] = (short)acc[mt][nt][r];
                    } else {
                        atomicAdd(&out[idx], (float)acc[mt][nt][r]);
                    }
                }
            }
        }
    }
}

extern "C" void kernel_launch(void* const* d_in, const int* in_sizes, int n_in,
                              void* d_out, int out_size, void* d_ws, size_t ws_size,
                              hipStream_t stream) {
    const float* x = (const float*)d_in[0];     // [8192, 12288]
    const float* w = (const float*)d_in[1];     // [1000, 12288]
    float* out = (float*)d_out;                 // [8192, 1000]
    unsigned char* ws = (unsigned char*)d_ws;

    pack_w_kernel<<<3072, 256, 0, stream>>>(w, ws);

    unsigned* part = reinterpret_cast<unsigned*>(ws + WS_W_BYTES);
    const bool use_part = ws_size >= WS_W_BYTES + WS_P_BYTES;
    if (use_part) {
        bgemm_kernel<1><<<512, 512, 0, stream>>>(x, ws, part, out);
        reduce_kernel<<<(B_ROWS * N_CLS) / (4 * 256), 256, 0, stream>>>(part, out);
    } else {
        zero_kernel<<<(B_ROWS * N_CLS) / (4 * 256), 256, 0, stream>>>(out);
        bgemm_kernel<0><<<512, 512, 0, stream>>>(x, ws, part, out);
    }
}